// Round 6
// baseline (774.600 us; speedup 1.0000x reference)
//
#include <hip/hip_runtime.h>

// FlowNetC correlation: B=8, C=256, H=96, W=128, PAD=20, S2=2, GW=21, NOUT=441
// out[b, dyi*21+j, y, x] = (1/256) * sum_c in1[b,c,y,x] * in2[b,c, y+2*dyi-20, x+2*j-20]
// Double-buffered LDS + async staging split (regs->LDS after barrier, loads under compute).
// CK=4: 25.6 KB LDS -> 6 blocks/CU for occupancy (round-5 fix; was 51.2 KB -> ~2 blocks/CU).

#define BDIM 128
#define CK 4

constexpr int Bn = 8, Cn = 256, Hn = 96, Wn = 128;
constexpr int GW = 21;            // displacement grid width
constexpr int NG = 6;             // dy groups of 4 -> 24 slots (21 valid)
constexpr int UP = 84;            // per-parity width of staged in2 row (u span 168)
constexpr int NITER = Cn / CK;    // 64
constexpr int NWG = Bn * Hn * NG; // 4608 blocks, divisible by 8 (XCDs)

#define NS2 6    // ceil(4*CK*42 float4-slots / 128 thr) = ceil(672/128)
#define NS1 1    // CK*32 float4-slots / 128 thr

__global__ __launch_bounds__(BDIM) void corr_kernel(
    const float* __restrict__ in1, const float* __restrict__ in2,
    float* __restrict__ out)
{
    // parity-split staging, double-buffered
    __shared__ __align__(16) float s1[2][CK][2][Wn / 2];
    __shared__ __align__(16) float s2[2][4][CK][2][UP];

    // bijective XCD-chunked swizzle
    int orig = blockIdx.x;
    int wg = (orig & 7) * (NWG / 8) + (orig >> 3);

    int g  = wg % NG;
    int by = wg / NG;
    int y  = by % Hn;
    int b  = by / Hn;

    int tid    = threadIdx.x;
    int dl     = tid >> 5;          // 0..3 : which dy in this group
    int dyi    = g * 4 + dl;        // 0..23 (valid if < 21)
    int lane32 = tid & 31;
    int parity = lane32 >> 4;       // 0: even x, 1: odd x
    int q      = lane32 & 15;       // owns x = 8q + parity + {0,2,4,6}

    const size_t chw = (size_t)Hn * Wn;
    const float* p1 = in1 + ((size_t)b * Cn) * chw + (size_t)y * Wn;
    const float* p2 = in2 + ((size_t)b * Cn) * chw;

    // ---- precompute vectorized staging slots (c0-independent) ----
    // s2: float4 slot idx over [4 dy][CK ch][42 vec], u = 4k-20; every float4 is
    //     fully in-bounds (5<=k<=36) or fully zero (20%4==0, 128%4==0).
    int v2_goff[NS2], v2_loff[NS2];
    {
        int y2d[4], rowv[4];
#pragma unroll
        for (int d = 0; d < 4; ++d) {
            int dyi2 = g * 4 + d;
            int y2   = y + dyi2 * 2 - 20;
            rowv[d]  = (dyi2 < GW) && (y2 >= 0) && (y2 < Hn);
            y2d[d]   = y2;
        }
#pragma unroll
        for (int s = 0; s < NS2; ++s) {
            int idx = tid + s * BDIM;            // valid < 4*CK*42 = 672
            if (idx < 4 * CK * 42) {
                int d  = idx / (CK * 42);
                int r  = idx - d * (CK * 42);
                int ch = r / 42;
                int k  = r - ch * 42;            // vec index; u = 4k - 20
                v2_loff[s] = ((d * CK + ch) * 2) * UP + 2 * k;   // parity0; parity1 at +UP
                v2_goff[s] = (rowv[d] && k >= 5 && k <= 36)
                           ? (ch * (int)chw + y2d[d] * Wn + 4 * k - 20) : -1;
            } else { v2_loff[s] = -1; v2_goff[s] = -1; }
        }
    }
    // s1: float4 slot over [CK ch][32 vec] -> exactly 1 per thread
    int v1_goff[NS1], v1_loff[NS1];
    {
        int ch = tid >> 5;
        int k  = tid & 31;
        v1_goff[0] = ch * (int)chw + 4 * k;
        v1_loff[0] = (ch * 2) * (Wn / 2) + 2 * k;
    }

    float acc[GW][4];
#pragma unroll
    for (int j = 0; j < GW; ++j)
#pragma unroll
        for (int i = 0; i < 4; ++i) acc[j][i] = 0.0f;

    float* s1base = &s1[0][0][0][0];
    float* s2base = &s2[0][0][0][0][0];
    constexpr int S1SZ = CK * 2 * (Wn / 2);   // floats per s1 buffer (512)
    constexpr int S2SZ = 4 * CK * 2 * UP;     // floats per s2 buffer (2688)

    float4 pf1[NS1], pf2[NS2];

    // issue global loads into registers (no vmcnt on the critical path)
    auto prefetch = [&](int c0) {
        size_t cadv = (size_t)c0 * chw;
#pragma unroll
        for (int s = 0; s < NS1; ++s)
            pf1[s] = *reinterpret_cast<const float4*>(p1 + cadv + v1_goff[s]);
#pragma unroll
        for (int s = 0; s < NS2; ++s) {
            float4 v{0.0f, 0.0f, 0.0f, 0.0f};
            if (v2_goff[s] >= 0)
                v = *reinterpret_cast<const float4*>(p2 + cadv + v2_goff[s]);
            pf2[s] = v;
        }
    };
    // parity-split LDS writes from the prefetch registers
    auto writeout = [&](int buf) {
        float* d1 = s1base + buf * S1SZ;
        float* d2 = s2base + buf * S2SZ;
#pragma unroll
        for (int s = 0; s < NS1; ++s) {
            float2 e{pf1[s].x, pf1[s].z};
            float2 o{pf1[s].y, pf1[s].w};
            *reinterpret_cast<float2*>(d1 + v1_loff[s]) = e;
            *reinterpret_cast<float2*>(d1 + v1_loff[s] + (Wn / 2)) = o;
        }
#pragma unroll
        for (int s = 0; s < NS2; ++s) {
            if (v2_loff[s] >= 0) {
                float2 e{pf2[s].x, pf2[s].z};
                float2 o{pf2[s].y, pf2[s].w};
                *reinterpret_cast<float2*>(d2 + v2_loff[s]) = e;
                *reinterpret_cast<float2*>(d2 + v2_loff[s] + UP) = o;
            }
        }
    };

    // ---- main loop: double-buffered, 1 barrier/iter ----
    prefetch(0);
    for (int it = 0; it < NITER; ++it) {
        int cur = it & 1;
        writeout(cur);                  // LDS writes of tile `it` (regs loaded last iter)
        __syncthreads();                // tile visible; all reads of buf cur drained
        if (it + 1 < NITER) prefetch((it + 1) * CK);   // loads in flight under compute

        const float* r1 = s1base + cur * S1SZ + parity * (Wn / 2) + 4 * q;
        const float* r2 = s2base + cur * S2SZ + (dl * CK * 2 + parity) * UP + 4 * q;
#pragma unroll
        for (int ch = 0; ch < CK; ++ch) {
            float4 a1v = *reinterpret_cast<const float4*>(r1 + ch * 2 * (Wn / 2));
            float a1[4] = {a1v.x, a1v.y, a1v.z, a1v.w};
            float b2[24];
#pragma unroll
            for (int kk = 0; kk < 6; ++kk) {
                float4 t = *reinterpret_cast<const float4*>(r2 + ch * 2 * UP + 4 * kk);
                b2[4 * kk + 0] = t.x; b2[4 * kk + 1] = t.y;
                b2[4 * kk + 2] = t.z; b2[4 * kk + 3] = t.w;
            }
#pragma unroll
            for (int j = 0; j < GW; ++j)
#pragma unroll
                for (int i = 0; i < 4; ++i)
                    acc[j][i] = fmaf(a1[i], b2[i + j], acc[j][i]);
        }
    }

    // ---- epilogue (WRITE_SIZE measured exactly minimal with this pattern) ----
    if (dyi < GW) {
        const float scale = 1.0f / 256.0f;
        int xb = 8 * q + parity;
#pragma unroll
        for (int j = 0; j < GW; ++j) {
            size_t o = (size_t)(b * (GW * GW) + dyi * GW + j);
            float* po = out + (o * Hn + y) * Wn + xb;
#pragma unroll
            for (int i = 0; i < 4; ++i)
                po[2 * i] = acc[j][i] * scale;
        }
    }
}

extern "C" void kernel_launch(void* const* d_in, const int* in_sizes, int n_in,
                              void* d_out, int out_size, void* d_ws, size_t ws_size,
                              hipStream_t stream) {
    const float* in1 = (const float*)d_in[0];
    const float* in2 = (const float*)d_in[1];
    float* out = (float*)d_out;
    corr_kernel<<<NWG, BDIM, 0, stream>>>(in1, in2, out);
}

// Round 9
// 349.193 us; speedup vs baseline: 2.2183x; 2.2183x over previous
//
#include <hip/hip_runtime.h>
#include <hip/hip_bf16.h>

// FlowNetC correlation via bf16 MFMA Gram (BISECT round: all 16 tiles, trivial epilogue).
// out[b, dyi*21+j, y, x] = (1/256) * sum_c in1[b,c,y,x] * in2[b,c,y2,x+2j-20], y2=y+2dyi-20.
// Parity split: x=2x'+p, u=2u'+p, u'=x'+j-10. Per (b,y,dyi,p):
//   G_p[x'][u'] = sum_c A_p[x'][c]*B_p[u'][c]  (64x64, K=256); store j=u'-x'+10 in [0,21).
// Block=(b,y,dyi), 4 waves: wave=(p,h); wave computes mt in {2h,2h+1} x nt 0..3 (all tiles).

typedef __attribute__((ext_vector_type(8))) short bf16x8;
typedef __attribute__((ext_vector_type(4))) float f32x4;

constexpr int Bn = 8, Cn = 256, Hn = 96, Wn = 128, GW = 21;
constexpr int KC = 32, NCH = Cn / KC;     // 8 chunks of 32 channels
constexpr int NWG = Bn * Hn * GW;         // 16128, divisible by 8
constexpr int CPX = NWG / 8;

__device__ inline unsigned pack_bf16(float lo, float hi) {
    __hip_bfloat16 l = __float2bfloat16(lo);
    __hip_bfloat16 h = __float2bfloat16(hi);
    unsigned short lu, hu;
    __builtin_memcpy(&lu, &l, 2);
    __builtin_memcpy(&hu, &h, 2);
    return (unsigned)lu | ((unsigned)hu << 16);
}

__global__ __launch_bounds__(256) void corr_mfma(
    const float* __restrict__ in1, const float* __restrict__ in2,
    float* __restrict__ out)
{
    // [dbuf][panel: Ae,Ao,Be,Bo][1024 uints]; panel = [mt4][kg4][pos16][ku4] of bf16x2
    __shared__ unsigned lds[2][4][1024];

    int orig = blockIdx.x;
    int wg  = (orig & 7) * CPX + (orig >> 3);   // bijective XCD chunking
    int dyi = wg % GW;
    int y   = (wg / GW) % Hn;
    int b   = wg / (GW * Hn);
    int y2  = y + 2 * dyi - 20;
    bool y2ok = (y2 >= 0) && (y2 < Hn);

    int tid = threadIdx.x;
    int w   = tid >> 6;          // wave 0..3
    int l   = tid & 63;
    int p   = w >> 1;            // parity
    int h   = w & 1;             // x-half: mt in {2h, 2h+1}
    int g   = l >> 4;            // k-group
    int m16 = l & 15;

    const size_t chw = (size_t)Hn * Wn;
    const float* pA = in1 + ((size_t)b * Cn) * chw + (size_t)y * Wn;
    const float* pB = in2 + ((size_t)b * Cn) * chw + (size_t)(y2ok ? y2 : 0) * Wn;

    int tm  = tid & 63;          // staging x-pair / u-pair position
    int tt0 = tid >> 6;          // staging c-pair base

    f32x4 acc[2][4] = {};        // acc[a][n] = tile (mt=2h+a, nt=n)
    float2 PA0[4][2], PB0[4][2], PA1[4][2], PB1[4][2];

    auto prefetch = [&](int chunk, float2 (&fA)[4][2], float2 (&fB)[4][2]) {
        size_t cadv = (size_t)(chunk * KC) * chw;
#pragma unroll
        for (int s = 0; s < 4; ++s) {
            int t = tt0 + 4 * s;                       // c-pair 0..15
            size_t off = cadv + (size_t)(2 * t) * chw + 2 * tm;
            fA[s][0] = *(const float2*)(pA + off);
            fA[s][1] = *(const float2*)(pA + off + chw);
            fB[s][0] = *(const float2*)(pB + off);
            fB[s][1] = *(const float2*)(pB + off + chw);
        }
    };

    auto writeout = [&](int buf, float2 (&fA)[4][2], float2 (&fB)[4][2]) {
#pragma unroll
        for (int s = 0; s < 4; ++s) {
            int t  = tt0 + 4 * s;
            int lo = ((tm >> 4) * 4 + (t >> 2)) * 64 + (tm & 15) * 4 + (t & 3);
            // low bf16 = channel 2t, high = 2t+1; .x = even x/u, .y = odd
            lds[buf][0][lo] = pack_bf16(fA[s][0].x, fA[s][1].x);
            lds[buf][1][lo] = pack_bf16(fA[s][0].y, fA[s][1].y);
            lds[buf][2][lo] = pack_bf16(fB[s][0].x, fB[s][1].x);
            lds[buf][3][lo] = pack_bf16(fB[s][0].y, fB[s][1].y);
        }
    };

    auto compute = [&](int buf) {
        const unsigned* Pa = &lds[buf][p][0];
        const unsigned* Pb = &lds[buf][2 + p][0];
        int fo = g * 64 + m16 * 4;
        bf16x8 A0  = *(const bf16x8*)(Pa + (2 * h + 0) * 256 + fo);
        bf16x8 A1  = *(const bf16x8*)(Pa + (2 * h + 1) * 256 + fo);
        bf16x8 Bf0 = *(const bf16x8*)(Pb + 0 * 256 + fo);
        bf16x8 Bf1 = *(const bf16x8*)(Pb + 1 * 256 + fo);
        bf16x8 Bf2 = *(const bf16x8*)(Pb + 2 * 256 + fo);
        bf16x8 Bf3 = *(const bf16x8*)(Pb + 3 * 256 + fo);
        acc[0][0] = __builtin_amdgcn_mfma_f32_16x16x32_bf16(A0, Bf0, acc[0][0], 0, 0, 0);
        acc[0][1] = __builtin_amdgcn_mfma_f32_16x16x32_bf16(A0, Bf1, acc[0][1], 0, 0, 0);
        acc[0][2] = __builtin_amdgcn_mfma_f32_16x16x32_bf16(A0, Bf2, acc[0][2], 0, 0, 0);
        acc[0][3] = __builtin_amdgcn_mfma_f32_16x16x32_bf16(A0, Bf3, acc[0][3], 0, 0, 0);
        acc[1][0] = __builtin_amdgcn_mfma_f32_16x16x32_bf16(A1, Bf0, acc[1][0], 0, 0, 0);
        acc[1][1] = __builtin_amdgcn_mfma_f32_16x16x32_bf16(A1, Bf1, acc[1][1], 0, 0, 0);
        acc[1][2] = __builtin_amdgcn_mfma_f32_16x16x32_bf16(A1, Bf2, acc[1][2], 0, 0, 0);
        acc[1][3] = __builtin_amdgcn_mfma_f32_16x16x32_bf16(A1, Bf3, acc[1][3], 0, 0, 0);
    };

    if (y2ok) {
        prefetch(0, PA0, PB0);
        prefetch(1, PA1, PB1);
        for (int it = 0; it < NCH; it += 2) {
            writeout(0, PA0, PB0);
            __syncthreads();
            if (it + 2 < NCH) prefetch(it + 2, PA0, PB0);
            compute(0);
            writeout(1, PA1, PB1);
            __syncthreads();
            if (it + 3 < NCH) prefetch(it + 3, PA1, PB1);
            compute(1);
        }
    }

    // ---- epilogue: every (j, x) written exactly once ----
    const float scale = 1.0f / 256.0f;
    unsigned base0 = (unsigned)(((b * (GW * GW) + dyi * GW) * Hn + y) * Wn);
    constexpr unsigned PLANE = (unsigned)(Hn * Wn);

#pragma unroll
    for (int a = 0; a < 2; ++a)
#pragma unroll
        for (int n = 0; n < 4; ++n)
#pragma unroll
            for (int r = 0; r < 4; ++r) {
                int xp = (2 * h + a) * 16 + g * 4 + r;   // x'  (C/D row, m89-verified)
                int up = n * 16 + m16;                   // u'  (C/D col)
                int j  = up - xp + 10;
                if ((unsigned)j < 21u)
                    out[base0 + (unsigned)j * PLANE + (unsigned)(2 * xp + p)] = acc[a][n][r] * scale;
            }

    // left edge zeros (u' < 0): j < 10, x' < 10-j — h==0 waves (both parities)
    if (h == 0) {
#pragma unroll
        for (int jj = 0; jj < 10; ++jj)
            if (l < 10 - jj)
                out[base0 + (unsigned)jj * PLANE + (unsigned)(2 * l + p)] = 0.0f;
    } else {
        // right edge zeros (u' >= 64): j > 10, x' >= 74-j — h==1 waves
#pragma unroll
        for (int jj = 11; jj < 21; ++jj)
            if (l < jj - 10)
                out[base0 + (unsigned)jj * PLANE + (unsigned)(2 * (74 - jj + l) + p)] = 0.0f;
    }
}

extern "C" void kernel_launch(void* const* d_in, const int* in_sizes, int n_in,
                              void* d_out, int out_size, void* d_ws, size_t ws_size,
                              hipStream_t stream) {
    const float* in1 = (const float*)d_in[0];
    const float* in2 = (const float*)d_in[1];
    float* out = (float*)d_out;
    corr_mfma<<<NWG, 256, 0, stream>>>(in1, in2, out);
}